// Round 1
// baseline (139.702 us; speedup 1.0000x reference)
//
#include <hip/hip_runtime.h>

typedef __bf16 bf16x8 __attribute__((ext_vector_type(8)));
typedef float f32x4 __attribute__((ext_vector_type(4)));

#define C_IN 128
#define HW_IN 3136      // 56*56
#define K_OUT 256
#define OWP 56          // padded output width
#define M_PER_IMG 3024  // 54*56
#define KG 1152         // 128*9
#define OUT_HW 2916     // 54*54

// ws layout (bytes):
//   [0,4)          : absmax bits (uint)
//   [4096, 593920) : Bt bf16 [256][1152], kk = (r*3+s)*128 + c
//   [593920, ...)  : xt bf16 [n][h][w][c] + 256-elem tail pad  (25.69 MB)

static __device__ __forceinline__ unsigned short f2bf(float f) {
  unsigned u = __float_as_uint(f);
  u += 0x7FFFu + ((u >> 16) & 1);   // RNE
  return (unsigned short)(u >> 16);
}

__global__ __launch_bounds__(256) void k_absmax(const float* __restrict__ w,
                                                unsigned* __restrict__ mx) {
  __shared__ float red[256];
  const int t = threadIdx.x;
  float v = fabsf(w[blockIdx.x * 256 + t]);
  red[t] = v;
  __syncthreads();
  for (int s = 128; s > 0; s >>= 1) {
    if (t < s) red[t] = fmaxf(red[t], red[t + s]);
    __syncthreads();
  }
  if (t == 0) atomicMax(mx, __float_as_uint(red[0]));
}

__global__ __launch_bounds__(256) void k_quant(const float* __restrict__ w,
                                               const unsigned* __restrict__ mx,
                                               unsigned short* __restrict__ bt) {
  const int idx = blockIdx.x * 256 + threadIdx.x;  // < 294912
  const float thr = 0.05f * __uint_as_float(*mx);
  const int k = idx / KG;
  const int j = idx - k * KG;
  const int rs = j >> 7;      // 0..8
  const int c = j & 127;
  const float v = w[k * KG + c * 9 + rs];
  float q = 0.f;
  if (v > thr) q = 1.f;
  else if (v < -thr) q = -1.f;
  bt[idx] = f2bf(q);
}

// x fp32 NCHW -> xt bf16 [n][hw][c], LDS tile transpose, XOR-swizzled (c^j)
__global__ __launch_bounds__(256) void k_xt(const float* __restrict__ x,
                                            unsigned short* __restrict__ xt) {
  __shared__ unsigned short tile[8192];  // [j:64][c:128], phys c = c ^ j
  const int n = blockIdx.x / 49;
  const int hw0 = (blockIdx.x - n * 49) * 64;
  const int t = threadIdx.x;
  const int j = t & 63;
  const int ci = t >> 6;
  const float* xp = x + (size_t)n * (C_IN * HW_IN) + hw0 + j;
#pragma unroll
  for (int it = 0; it < 32; ++it) {
    const int c = it * 4 + ci;
    tile[j * 128 + (c ^ j)] = f2bf(xp[(size_t)c * HW_IN]);
  }
  __syncthreads();
  const int jj = t >> 2;
  const int q = t & 3;
  unsigned short v[32] __attribute__((aligned(16)));
#pragma unroll
  for (int i = 0; i < 32; ++i)
    v[i] = tile[jj * 128 + ((q * 32 + i) ^ jj)];
  uint4* dst = (uint4*)(xt + (size_t)(n * HW_IN + hw0 + jj) * 128 + q * 32);
#pragma unroll
  for (int u = 0; u < 4; ++u)
    dst[u] = *(const uint4*)&v[u * 8];
}

// GEMM: D[kch][m] = sum_kk Bt[kch][kk] * A[m][kk]
// tile 128 kch x 128 spatial, BK=32, 4 waves (2k x 2sp), 16x16x32 bf16 MFMA
__global__ __launch_bounds__(256) void k_conv(const unsigned short* __restrict__ xt,
                                              const unsigned short* __restrict__ bt,
                                              const float* __restrict__ bias,
                                              float* __restrict__ out) {
  __shared__ unsigned short Ws[4096];  // [kc:128][kk:32], chunk-swizzled
  __shared__ unsigned short Xs[4096];  // [m :128][kk:32], chunk-swizzled
  const int t = threadIdx.x;
  const int bid = blockIdx.x;
  const int kt = bid & 1;    // k-channel tile (0/1)
  const int spt = bid >> 1;  // spatial tile 0..755

  // ---- staging setup: thread stages chunk (row r0,h0) and (row r0+64,h0) of both tiles
  const int r0 = t >> 2;
  const int h0 = t & 3;
  const int m0 = spt * 128 + r0;
  const int m1 = m0 + 64;
  const int n0 = m0 / M_PER_IMG;
  const int n1 = m1 / M_PER_IMG;
  const unsigned short* xsrc0 = xt + (size_t)(m0 + 112 * n0) * 128 + h0 * 8;
  const unsigned short* xsrc1 = xt + (size_t)(m1 + 112 * n1) * 128 + h0 * 8;
  const unsigned short* wsrc0 = bt + (size_t)(kt * 128 + r0) * KG + h0 * 8;
  const unsigned short* wsrc1 = wsrc0 + (size_t)64 * KG;
  const int sw0 = (r0 >> 1) & 3;
  const int lw0 = r0 * 32 + ((h0 ^ sw0) << 3);   // ushort offset
  const int lw1 = lw0 + 64 * 32;                 // (r0+64) has same swizzle

  // ---- fragment read setup
  const int l = t & 63;
  const int wv = t >> 6;
  const int wk = wv >> 1;   // k half
  const int wsp = wv & 1;   // spatial half
  const int lr = l & 15;
  const int hh = l >> 4;
  const int fchunk = ((hh ^ ((lr >> 1) & 3)) << 3);
  int wro[4], xro[4];
#pragma unroll
  for (int f = 0; f < 4; ++f) {
    wro[f] = (wk * 64 + f * 16 + lr) * 32 + fchunk;
    xro[f] = (wsp * 64 + f * 16 + lr) * 32 + fchunk;
  }

  f32x4 acc[4][4];
#pragma unroll
  for (int i = 0; i < 4; ++i)
#pragma unroll
    for (int jq = 0; jq < 4; ++jq)
      acc[i][jq] = (f32x4){0.f, 0.f, 0.f, 0.f};

  for (int kb = 0; kb < 36; ++kb) {
    const int rs = kb >> 2;
    const int c0 = (kb & 3) << 5;
    const int xoff = ((rs / 3) * 56 + (rs % 3)) * 128 + c0;
    const int woff = kb * 32;
    uint4 xa = *(const uint4*)(xsrc0 + xoff);
    uint4 xb = *(const uint4*)(xsrc1 + xoff);
    uint4 wa = *(const uint4*)(wsrc0 + woff);
    uint4 wb = *(const uint4*)(wsrc1 + woff);
    __syncthreads();   // previous tile's reads complete
    *(uint4*)&Xs[lw0] = xa;
    *(uint4*)&Xs[lw1] = xb;
    *(uint4*)&Ws[lw0] = wa;
    *(uint4*)&Ws[lw1] = wb;
    __syncthreads();
    bf16x8 wf[4], xf[4];
#pragma unroll
    for (int f = 0; f < 4; ++f) {
      wf[f] = *(const bf16x8*)&Ws[wro[f]];
      xf[f] = *(const bf16x8*)&Xs[xro[f]];
    }
#pragma unroll
    for (int fi = 0; fi < 4; ++fi)
#pragma unroll
      for (int fj = 0; fj < 4; ++fj)
        acc[fi][fj] = __builtin_amdgcn_mfma_f32_16x16x32_bf16(wf[fi], xf[fj], acc[fi][fj], 0, 0, 0);
  }

  // ---- epilogue: D row=(lane>>4)*4+reg -> k channel; col=lane&15 -> spatial
  float bv[4][4];
#pragma unroll
  for (int fi = 0; fi < 4; ++fi)
#pragma unroll
    for (int rg = 0; rg < 4; ++rg)
      bv[fi][rg] = bias[kt * 128 + wk * 64 + fi * 16 + hh * 4 + rg];

#pragma unroll
  for (int fj = 0; fj < 4; ++fj) {
    const int m = spt * 128 + wsp * 64 + fj * 16 + lr;
    const int ni = m / M_PER_IMG;
    const int rem = m - ni * M_PER_IMG;
    const int oh = rem / OWP;
    const int ow = rem - oh * OWP;
    if (ow < 54) {
      float* op = out + (size_t)ni * (K_OUT * OUT_HW) + oh * 54 + ow;
#pragma unroll
      for (int fi = 0; fi < 4; ++fi) {
        const int kbase = kt * 128 + wk * 64 + fi * 16 + hh * 4;
#pragma unroll
        for (int rg = 0; rg < 4; ++rg)
          op[(size_t)(kbase + rg) * OUT_HW] = acc[fi][fj][rg] + bv[fi][rg];
      }
    }
  }
}

extern "C" void kernel_launch(void* const* d_in, const int* in_sizes, int n_in,
                              void* d_out, int out_size, void* d_ws, size_t ws_size,
                              hipStream_t stream) {
  const float* x = (const float*)d_in[0];
  const float* w = (const float*)d_in[1];
  const float* bias = (const float*)d_in[2];
  float* out = (float*)d_out;
  unsigned char* ws = (unsigned char*)d_ws;
  unsigned* mx = (unsigned*)ws;
  unsigned short* bt = (unsigned short*)(ws + 4096);
  unsigned short* xt = (unsigned short*)(ws + 593920);

  hipMemsetAsync(mx, 0, 4, stream);
  k_absmax<<<1152, 256, 0, stream>>>(w, mx);           // 294912 / 256
  k_quant<<<1152, 256, 0, stream>>>(w, mx, bt);
  k_xt<<<32 * 49, 256, 0, stream>>>(x, xt);
  k_conv<<<756 * 2, 256, 0, stream>>>(xt, bt, bias, out);
}

// Round 2
// 126.846 us; speedup vs baseline: 1.1013x; 1.1013x over previous
//
#include <hip/hip_runtime.h>

typedef __bf16 bf16x8 __attribute__((ext_vector_type(8)));
typedef float f32x4 __attribute__((ext_vector_type(4)));

#define C_IN 128
#define HW_IN 3136      // 56*56
#define K_OUT 256
#define OWP 56          // padded output width
#define M_PER_IMG 3024  // 54*56
#define KG 1152         // 128*9
#define OUT_HW 2916     // 54*54

// ws layout (bytes):
//   [0,4)          : absmax bits (uint)
//   [4096, 593920) : Bt bf16 [256][1152], kk = (r*3+s)*128 + c
//   [593920, ...)  : xt bf16 [n][h][w][c] + tail pad  (25.69 MB)

static __device__ __forceinline__ unsigned short f2bf(float f) {
  unsigned u = __float_as_uint(f);
  u += 0x7FFFu + ((u >> 16) & 1);   // RNE
  return (unsigned short)(u >> 16);
}

// async global->LDS, 16B per lane; dest = wave-uniform base + lane*16
static __device__ __forceinline__ void gload16(const unsigned short* g, unsigned short* l) {
  __builtin_amdgcn_global_load_lds(
      (const __attribute__((address_space(1))) unsigned int*)g,
      (__attribute__((address_space(3))) unsigned int*)l, 16, 0, 0);
}

__global__ __launch_bounds__(256) void k_absmax(const float* __restrict__ w,
                                                unsigned* __restrict__ mx) {
  __shared__ float red[256];
  const int t = threadIdx.x;
  float v = fabsf(w[blockIdx.x * 256 + t]);
  red[t] = v;
  __syncthreads();
  for (int s = 128; s > 0; s >>= 1) {
    if (t < s) red[t] = fmaxf(red[t], red[t + s]);
    __syncthreads();
  }
  if (t == 0) atomicMax(mx, __float_as_uint(red[0]));
}

__global__ __launch_bounds__(256) void k_quant(const float* __restrict__ w,
                                               const unsigned* __restrict__ mx,
                                               unsigned short* __restrict__ bt) {
  const int idx = blockIdx.x * 256 + threadIdx.x;  // < 294912
  const float thr = 0.05f * __uint_as_float(*mx);
  const int k = idx / KG;
  const int j = idx - k * KG;
  const int rs = j >> 7;      // 0..8
  const int c = j & 127;
  const float v = w[k * KG + c * 9 + rs];
  float q = 0.f;
  if (v > thr) q = 1.f;
  else if (v < -thr) q = -1.f;
  bt[idx] = f2bf(q);
}

// x fp32 NCHW -> xt bf16 [n][hw][c], LDS tile transpose, XOR-swizzled (c^j)
__global__ __launch_bounds__(256) void k_xt(const float* __restrict__ x,
                                            unsigned short* __restrict__ xt) {
  __shared__ unsigned short tile[8192];  // [j:64][c:128], phys c = c ^ j
  const int n = blockIdx.x / 49;
  const int hw0 = (blockIdx.x - n * 49) * 64;
  const int t = threadIdx.x;
  const int j = t & 63;
  const int ci = t >> 6;
  const float* xp = x + (size_t)n * (C_IN * HW_IN) + hw0 + j;
#pragma unroll
  for (int it = 0; it < 32; ++it) {
    const int c = it * 4 + ci;
    tile[j * 128 + (c ^ j)] = f2bf(xp[(size_t)c * HW_IN]);
  }
  __syncthreads();
  const int jj = t >> 2;
  const int q = t & 3;
  unsigned short v[32] __attribute__((aligned(16)));
#pragma unroll
  for (int i = 0; i < 32; ++i)
    v[i] = tile[jj * 128 + ((q * 32 + i) ^ jj)];
  uint4* dst = (uint4*)(xt + (size_t)(n * HW_IN + hw0 + jj) * 128 + q * 32);
#pragma unroll
  for (int u = 0; u < 4; ++u)
    dst[u] = *(const uint4*)&v[u * 8];
}

// GEMM: D[kch][m] = sum_kk Bt[kch][kk] * A[m][kk]
// tile 128 kch x 128 spatial, BK=32, 4 waves (2k x 2sp), 16x16x32 bf16 MFMA
// staging via global_load_lds: linear LDS dest, chunk-swizzle baked into the
// per-lane GLOBAL source address (m173/m201 pattern); reads use same swizzle.
__global__ __launch_bounds__(256) void k_conv(const unsigned short* __restrict__ xt,
                                              const unsigned short* __restrict__ bt,
                                              const float* __restrict__ bias,
                                              float* __restrict__ out) {
  __shared__ unsigned short Ws[4096];  // [kc:128][kk:32], chunk-swizzled
  __shared__ unsigned short Xs[4096];  // [m :128][kk:32], chunk-swizzled
  const int t = threadIdx.x;
  const int bid = blockIdx.x;
  const int kt = bid & 1;    // k-channel tile (0/1)
  const int spt = bid >> 1;  // spatial tile 0..755

  // ---- staging setup: lane (r0,h0) sources logical chunk h0^sw0 of its row
  const int r0 = t >> 2;
  const int h0 = t & 3;
  const int sw0 = (r0 >> 1) & 3;
  const int hs = (h0 ^ sw0) * 8;      // swizzled chunk offset (shorts)
  const int m0 = spt * 128 + r0;
  const int m1 = m0 + 64;
  const int n0 = m0 / M_PER_IMG;
  const int n1 = m1 / M_PER_IMG;
  const unsigned short* xsrc0 = xt + (size_t)(m0 + 112 * n0) * 128 + hs;
  const unsigned short* xsrc1 = xt + (size_t)(m1 + 112 * n1) * 128 + hs;
  const unsigned short* wsrc0 = bt + (size_t)(kt * 128 + r0) * KG + hs;
  const unsigned short* wsrc1 = wsrc0 + (size_t)64 * KG;
  const int wvb = (t >> 6) * 512;     // wave's linear LDS region (shorts)

  // ---- fragment read setup (phys chunk of logical chunk hh in row r is hh^((r>>1)&3))
  const int l = t & 63;
  const int wv = t >> 6;
  const int wk = wv >> 1;   // k half
  const int wsp = wv & 1;   // spatial half
  const int lr = l & 15;
  const int hh = l >> 4;
  const int fchunk = ((hh ^ ((lr >> 1) & 3)) << 3);
  int wro[4], xro[4];
#pragma unroll
  for (int f = 0; f < 4; ++f) {
    wro[f] = (wk * 64 + f * 16 + lr) * 32 + fchunk;
    xro[f] = (wsp * 64 + f * 16 + lr) * 32 + fchunk;
  }

  f32x4 acc[4][4];
#pragma unroll
  for (int i = 0; i < 4; ++i)
#pragma unroll
    for (int jq = 0; jq < 4; ++jq)
      acc[i][jq] = (f32x4){0.f, 0.f, 0.f, 0.f};

  for (int kb = 0; kb < 36; ++kb) {
    const int rs = kb >> 2;
    const int c0 = (kb & 3) << 5;
    const int xoff = ((rs / 3) * 56 + (rs % 3)) * 128 + c0;
    const int woff = kb * 32;
    __syncthreads();   // previous tile's reads complete before overwrite
    gload16(xsrc0 + xoff, &Xs[wvb]);
    gload16(xsrc1 + xoff, &Xs[2048 + wvb]);
    gload16(wsrc0 + woff, &Ws[wvb]);
    gload16(wsrc1 + woff, &Ws[2048 + wvb]);
    __syncthreads();   // drains vmcnt(0): staged data visible
    bf16x8 wf[4], xf[4];
#pragma unroll
    for (int f = 0; f < 4; ++f) {
      wf[f] = *(const bf16x8*)&Ws[wro[f]];
      xf[f] = *(const bf16x8*)&Xs[xro[f]];
    }
#pragma unroll
    for (int fi = 0; fi < 4; ++fi)
#pragma unroll
      for (int fj = 0; fj < 4; ++fj)
        acc[fi][fj] = __builtin_amdgcn_mfma_f32_16x16x32_bf16(wf[fi], xf[fj], acc[fi][fj], 0, 0, 0);
  }

  // ---- epilogue: D row=(lane>>4)*4+reg -> k channel; col=lane&15 -> spatial
  float bv[4][4];
#pragma unroll
  for (int fi = 0; fi < 4; ++fi)
#pragma unroll
    for (int rg = 0; rg < 4; ++rg)
      bv[fi][rg] = bias[kt * 128 + wk * 64 + fi * 16 + hh * 4 + rg];

#pragma unroll
  for (int fj = 0; fj < 4; ++fj) {
    const int m = spt * 128 + wsp * 64 + fj * 16 + lr;
    const int ni = m / M_PER_IMG;
    const int rem = m - ni * M_PER_IMG;
    const int oh = rem / OWP;
    const int ow = rem - oh * OWP;
    if (ow < 54) {
      float* op = out + (size_t)ni * (K_OUT * OUT_HW) + oh * 54 + ow;
#pragma unroll
      for (int fi = 0; fi < 4; ++fi) {
        const int kbase = kt * 128 + wk * 64 + fi * 16 + hh * 4;
#pragma unroll
        for (int rg = 0; rg < 4; ++rg)
          op[(size_t)(kbase + rg) * OUT_HW] = acc[fi][fj][rg] + bv[fi][rg];
      }
    }
  }
}

extern "C" void kernel_launch(void* const* d_in, const int* in_sizes, int n_in,
                              void* d_out, int out_size, void* d_ws, size_t ws_size,
                              hipStream_t stream) {
  const float* x = (const float*)d_in[0];
  const float* w = (const float*)d_in[1];
  const float* bias = (const float*)d_in[2];
  float* out = (float*)d_out;
  unsigned char* ws = (unsigned char*)d_ws;
  unsigned* mx = (unsigned*)ws;
  unsigned short* bt = (unsigned short*)(ws + 4096);
  unsigned short* xt = (unsigned short*)(ws + 593920);

  hipMemsetAsync(mx, 0, 4, stream);
  k_absmax<<<1152, 256, 0, stream>>>(w, mx);           // 294912 / 256
  k_quant<<<1152, 256, 0, stream>>>(w, mx, bt);
  k_xt<<<32 * 49, 256, 0, stream>>>(x, xt);
  k_conv<<<756 * 2, 256, 0, stream>>>(xt, bt, bias, out);
}